// Round 5
// baseline (3245.778 us; speedup 1.0000x reference)
//
#include <hip/hip_runtime.h>
#include <math.h>

#define BB   64
#define NIN  512
#define NH   512
#define TT   512

typedef _Float16 half2_t __attribute__((ext_vector_type(2)));
typedef _Float16 half8_t __attribute__((ext_vector_type(8)));
typedef float    f32x4  __attribute__((ext_vector_type(4)));

__device__ __forceinline__ unsigned pk16(float x, float y) {
    unsigned lo = (unsigned)__builtin_bit_cast(unsigned short, (_Float16)x);
    unsigned hi = (unsigned)__builtin_bit_cast(unsigned short, (_Float16)y);
    return lo | (hi << 16);
}

__device__ __forceinline__ float dot2u(unsigned w, unsigned a, float acc) {
    return __builtin_amdgcn_fdot2(__builtin_bit_cast(half2_t, w),
                                  __builtin_bit_cast(half2_t, a), acc, false);
}

__device__ __forceinline__ float tanh_fast(float x) {
    float ax = __builtin_fabsf(x);
    float e  = __builtin_amdgcn_exp2f(-2.885390082f * ax);   // exp(-2|x|)
    float r  = (1.0f - e) * __builtin_amdgcn_rcpf(1.0f + e);
    return __builtin_copysignf(r, x);
}

// ---------------------------------------------------------------------------
// K0: pack X and Wax into half2-pair dwords (unchanged, verified).
// ---------------------------------------------------------------------------
#define NX4 (BB * (NIN / 2) * (TT / 4))
#define NW4 ((NIN / 2) * (NH / 4))

__global__ __launch_bounds__(256) void pack_f16(
    const float* __restrict__ X, const float* __restrict__ Wax,
    unsigned* __restrict__ Xp, unsigned* __restrict__ Wp)
{
    const int gid = blockIdx.x * 256 + threadIdx.x;
    if (gid < NX4) {
        const int t4 = gid & (TT / 4 - 1);
        const int pr = gid >> 7;
        const int j  = pr & (NIN / 2 - 1);
        const int b  = pr >> 8;
        float4 r0 = *(const float4*)&X[((size_t)b * NIN + 2 * j    ) * TT + t4 * 4];
        float4 r1 = *(const float4*)&X[((size_t)b * NIN + 2 * j + 1) * TT + t4 * 4];
        uint4 o;
        o.x = pk16(r0.x, r1.x); o.y = pk16(r0.y, r1.y);
        o.z = pk16(r0.z, r1.z); o.w = pk16(r0.w, r1.w);
        *(uint4*)&Xp[(size_t)pr * TT + t4 * 4] = o;
    } else {
        const int g = gid - NX4;
        if (g < NW4) {
            const int h4 = g & (NH / 4 - 1);
            const int j  = g >> 7;
            float4 r0 = *(const float4*)&Wax[((size_t)(2 * j    )) * NH + h4 * 4];
            float4 r1 = *(const float4*)&Wax[((size_t)(2 * j + 1)) * NH + h4 * 4];
            uint4 o;
            o.x = pk16(r0.x, r1.x); o.y = pk16(r0.y, r1.y);
            o.z = pk16(r0.z, r1.z); o.w = pk16(r0.w, r1.w);
            *(uint4*)&Wp[(size_t)j * NH + h4 * 4] = o;
        }
    }
}

// ---------------------------------------------------------------------------
// K1' (MFMA, packed inputs) — unchanged, verified.
// ---------------------------------------------------------------------------
__global__ __launch_bounds__(256) void inp_proj_mfma_pk(
    const unsigned* __restrict__ Xp, const unsigned* __restrict__ Wp,
    const float* __restrict__ bx, const float* __restrict__ ba,
    float* __restrict__ out)
{
    __shared__ unsigned Xsp[16][132];
    __shared__ unsigned Wsp[16][132];

    const int b   = blockIdx.z;
    const int t0  = blockIdx.y * 128;
    const int h0  = blockIdx.x * 128;
    const int tid = threadIdx.x;
    const int lane = tid & 63;
    const int wid  = tid >> 6;
    const int wm   = wid >> 1;
    const int wn   = wid & 1;
    const int q    = lane >> 4;
    const int r16  = lane & 15;

    const int lr = tid >> 4;
    const int lc = (tid & 15) * 8;

    const unsigned* Xb = Xp + (size_t)b * (NIN / 2) * TT;

    f32x4 acc[4][4] = {};

    for (int p0 = 0; p0 < NIN / 2; p0 += 16) {
        const unsigned* Arow = &Xb[(size_t)(p0 + lr) * TT + t0 + lc];
        const unsigned* Brow = &Wp[(size_t)(p0 + lr) * NH + h0 + lc];
        uint4 xa = *(const uint4*)&Arow[0];
        uint4 xb = *(const uint4*)&Arow[4];
        uint4 wa = *(const uint4*)&Brow[0];
        uint4 wb = *(const uint4*)&Brow[4];

        __syncthreads();
        *(uint4*)&Xsp[lr][lc]     = xa;
        *(uint4*)&Xsp[lr][lc + 4] = xb;
        *(uint4*)&Wsp[lr][lc]     = wa;
        *(uint4*)&Wsp[lr][lc + 4] = wb;
        __syncthreads();

        uint4 af[4], bf[4];
#pragma unroll
        for (int mt = 0; mt < 4; ++mt) {
            const int tc = wm * 64 + mt * 16 + r16;
            af[mt].x = Xsp[4 * q + 0][tc];
            af[mt].y = Xsp[4 * q + 1][tc];
            af[mt].z = Xsp[4 * q + 2][tc];
            af[mt].w = Xsp[4 * q + 3][tc];
        }
#pragma unroll
        for (int nt = 0; nt < 4; ++nt) {
            const int hc = wn * 64 + nt * 16 + r16;
            bf[nt].x = Wsp[4 * q + 0][hc];
            bf[nt].y = Wsp[4 * q + 1][hc];
            bf[nt].z = Wsp[4 * q + 2][hc];
            bf[nt].w = Wsp[4 * q + 3][hc];
        }
#pragma unroll
        for (int mt = 0; mt < 4; ++mt)
#pragma unroll
            for (int nt = 0; nt < 4; ++nt)
                acc[mt][nt] = __builtin_amdgcn_mfma_f32_16x16x32_f16(
                    __builtin_bit_cast(half8_t, af[mt]),
                    __builtin_bit_cast(half8_t, bf[nt]),
                    acc[mt][nt], 0, 0, 0);
    }

#pragma unroll
    for (int nt = 0; nt < 4; ++nt) {
        const int h = h0 + wn * 64 + nt * 16 + r16;
        const float bias = bx[h] + ba[h];
#pragma unroll
        for (int mt = 0; mt < 4; ++mt) {
            const int trow = t0 + wm * 64 + mt * 16 + q * 4;
#pragma unroll
            for (int rr = 0; rr < 4; ++rr) {
                out[(size_t)(trow + rr) * (BB * NH) + (size_t)b * NH + h] =
                    acc[mt][nt][rr] + bias;
            }
        }
    }
}

// ---------------------------------------------------------------------------
// K1 fallback (f32 inputs) — used only if ws too small. Unchanged.
// ---------------------------------------------------------------------------
__global__ __launch_bounds__(256) void inp_proj_mfma(
    const float* __restrict__ X, const float* __restrict__ Wax,
    const float* __restrict__ bx, const float* __restrict__ ba,
    float* __restrict__ out)
{
    __shared__ unsigned Xsp[16][132];
    __shared__ unsigned Wsp[16][132];

    const int b   = blockIdx.z;
    const int t0  = blockIdx.y * 128;
    const int h0  = blockIdx.x * 128;
    const int tid = threadIdx.x;
    const int lane = tid & 63;
    const int wid  = tid >> 6;
    const int wm   = wid >> 1;
    const int wn   = wid & 1;
    const int q    = lane >> 4;
    const int r16  = lane & 15;

    const int lr = tid >> 4;
    const int lc = (tid & 15) * 8;

    const float* Xb = X + (size_t)b * NIN * TT;

    f32x4 acc[4][4] = {};

    for (int i0 = 0; i0 < NIN; i0 += 32) {
        const int k0 = i0 + 2 * lr, k1 = k0 + 1;
        float4 xa0 = *(const float4*)&Xb[(size_t)k0 * TT + t0 + lc];
        float4 xa1 = *(const float4*)&Xb[(size_t)k0 * TT + t0 + lc + 4];
        float4 xb0 = *(const float4*)&Xb[(size_t)k1 * TT + t0 + lc];
        float4 xb1 = *(const float4*)&Xb[(size_t)k1 * TT + t0 + lc + 4];
        float4 wa0 = *(const float4*)&Wax[(size_t)k0 * NH + h0 + lc];
        float4 wa1 = *(const float4*)&Wax[(size_t)k0 * NH + h0 + lc + 4];
        float4 wb0 = *(const float4*)&Wax[(size_t)k1 * NH + h0 + lc];
        float4 wb1 = *(const float4*)&Wax[(size_t)k1 * NH + h0 + lc + 4];

        uint4 xp0, xp1, wp0, wp1;
        xp0.x = pk16(xa0.x, xb0.x); xp0.y = pk16(xa0.y, xb0.y);
        xp0.z = pk16(xa0.z, xb0.z); xp0.w = pk16(xa0.w, xb0.w);
        xp1.x = pk16(xa1.x, xb1.x); xp1.y = pk16(xa1.y, xb1.y);
        xp1.z = pk16(xa1.z, xb1.z); xp1.w = pk16(xa1.w, xb1.w);
        wp0.x = pk16(wa0.x, wb0.x); wp0.y = pk16(wa0.y, wb0.y);
        wp0.z = pk16(wa0.z, wb0.z); wp0.w = pk16(wa0.w, wb0.w);
        wp1.x = pk16(wa1.x, wb1.x); wp1.y = pk16(wa1.y, wb1.y);
        wp1.z = pk16(wa1.z, wb1.z); wp1.w = pk16(wa1.w, wb1.w);

        __syncthreads();
        *(uint4*)&Xsp[lr][lc]     = xp0;
        *(uint4*)&Xsp[lr][lc + 4] = xp1;
        *(uint4*)&Wsp[lr][lc]     = wp0;
        *(uint4*)&Wsp[lr][lc + 4] = wp1;
        __syncthreads();

        uint4 af[4], bf[4];
#pragma unroll
        for (int mt = 0; mt < 4; ++mt) {
            const int tc = wm * 64 + mt * 16 + r16;
            af[mt].x = Xsp[4 * q + 0][tc];
            af[mt].y = Xsp[4 * q + 1][tc];
            af[mt].z = Xsp[4 * q + 2][tc];
            af[mt].w = Xsp[4 * q + 3][tc];
        }
#pragma unroll
        for (int nt = 0; nt < 4; ++nt) {
            const int hc = wn * 64 + nt * 16 + r16;
            bf[nt].x = Wsp[4 * q + 0][hc];
            bf[nt].y = Wsp[4 * q + 1][hc];
            bf[nt].z = Wsp[4 * q + 2][hc];
            bf[nt].w = Wsp[4 * q + 3][hc];
        }
#pragma unroll
        for (int mt = 0; mt < 4; ++mt)
#pragma unroll
            for (int nt = 0; nt < 4; ++nt)
                acc[mt][nt] = __builtin_amdgcn_mfma_f32_16x16x32_f16(
                    __builtin_bit_cast(half8_t, af[mt]),
                    __builtin_bit_cast(half8_t, bf[nt]),
                    acc[mt][nt], 0, 0, 0);
    }

#pragma unroll
    for (int nt = 0; nt < 4; ++nt) {
        const int h = h0 + wn * 64 + nt * 16 + r16;
        const float bias = bx[h] + ba[h];
#pragma unroll
        for (int mt = 0; mt < 4; ++mt) {
            const int trow = t0 + wm * 64 + mt * 16 + q * 4;
#pragma unroll
            for (int rr = 0; rr < 4; ++rr) {
                out[(size_t)(trow + rr) * (BB * NH) + (size_t)b * NH + h] =
                    acc[mt][nt][rr] + bias;
            }
        }
    }
}

// ---------------------------------------------------------------------------
// K2 v8: 1024 threads, ONE barrier/step, atomic LDS reduce, a_t in REGISTER.
// Thread (kq=tid>>7, cidx=tid&127) owns 4 columns {cidx,+128,+256,+384} over
// its k-eighth (24 pairs VGPR, 8 pairs LDS uint4). Partials: 4 conflict-free
// atomicAdd (ds_add_f32, lane-contiguous) into rotating part[3][512].
// After the single barrier each thread reads ONLY its own 2 columns
// (h2 = kq*64+2*(tid&31), 1 ds_read_b64, broadcast), adds u, tanh x2,
// pk16 -> a_loc register (next step's dots start immediately; no a_lds).
// 3-buffer rotation makes zeroing race-free with one barrier: buf read at
// step t is zeroed at step t (after barrier t) and next added at step t+2
// (after barrier t+1). Stores/zeros gated to lanes<32 of even waves.
// ---------------------------------------------------------------------------
#define NRP 24        // register-resident pairs per column
#define NLP 8         // LDS-resident pairs per column (uint4 rows)

__device__ __forceinline__ unsigned bline(unsigned a, int l) {
    return (unsigned)__builtin_amdgcn_readlane((int)a, l);
}

__global__ __launch_bounds__(1024, 4) void rnn_scan_v8(
    const float* __restrict__ Waa, float* __restrict__ out)
{
    __shared__ uint4 wldsv[NLP][1024];       // 128 KB [pair][tid] = 4 cols
    __shared__ float part[3][512];           // 6 KB rotating partial sums

    const int tid  = threadIdx.x;
    const int b    = blockIdx.x;
    const int cidx = tid & 127;
    const int kq   = tid >> 7;               // k-eighth 0..7
    const int l32  = tid & 31;
    const int wv   = tid >> 6;

    // ---- preamble: 4 columns {cidx,+128,+256,+384} x 32 pairs ----
    unsigned w0[NRP], w1[NRP], w2[NRP], w3[NRP];
#pragma unroll
    for (int j = 0; j < NRP; ++j) {
        const int k = kq * 64 + 2 * j;
        const float* r0 = &Waa[(size_t)k * NH + cidx];
        const float* r1 = &Waa[(size_t)(k + 1) * NH + cidx];
        w0[j] = pk16(r0[0],   r1[0]);
        w1[j] = pk16(r0[128], r1[128]);
        w2[j] = pk16(r0[256], r1[256]);
        w3[j] = pk16(r0[384], r1[384]);
    }
#pragma unroll
    for (int p = 0; p < NLP; ++p) {
        const int k = kq * 64 + 2 * (NRP + p);
        const float* r0 = &Waa[(size_t)k * NH + cidx];
        const float* r1 = &Waa[(size_t)(k + 1) * NH + cidx];
        uint4 wvv;
        wvv.x = pk16(r0[0],   r1[0]);
        wvv.y = pk16(r0[128], r1[128]);
        wvv.z = pk16(r0[256], r1[256]);
        wvv.w = pk16(r0[384], r1[384]);
        wldsv[p][tid] = wvv;
    }

    if (tid < 512) {                         // zero all 3 part buffers
        part[0][tid] = 0.0f;
        part[1][tid] = 0.0f;
        part[2][tid] = 0.0f;
    }
    __syncthreads();

    // this thread's a-pair columns
    const int h2 = kq * 64 + 2 * l32;
    const float* ub = out + (size_t)b * NH + h2;
    float2 u_cur = *(const float2*)ub;
    unsigned a_loc = 0u;                     // a_0 = 0 (packed f16 pair)
    const bool gate = ((tid & 32) == 0) && ((wv & 1) == 0);

    int pb = 0;
    for (int t = 0; t < TT; ++t) {
        const int tn = (t + 1 < TT) ? (t + 1) : (TT - 1);
        float2 u_next = *(const float2*)&ub[(size_t)tn * (BB * NH)]; // prefetch

        float acc0 = 0.f, acc1 = 0.f, acc2 = 0.f, acc3 = 0.f;
#pragma unroll
        for (int j = 0; j < NRP; j += 2) {
            unsigned ra = bline(a_loc, j);
            unsigned rb = bline(a_loc, j + 1);
            acc0 = dot2u(w0[j], ra, acc0);
            acc1 = dot2u(w1[j], ra, acc1);
            acc2 = dot2u(w2[j], ra, acc2);
            acc3 = dot2u(w3[j], ra, acc3);
            acc0 = dot2u(w0[j + 1], rb, acc0);
            acc1 = dot2u(w1[j + 1], rb, acc1);
            acc2 = dot2u(w2[j + 1], rb, acc2);
            acc3 = dot2u(w3[j + 1], rb, acc3);
        }
#pragma unroll
        for (int p = 0; p < NLP; ++p) {
            unsigned ra = bline(a_loc, NRP + p);
            uint4 v = wldsv[p][tid];
            acc0 = dot2u(v.x, ra, acc0);
            acc1 = dot2u(v.y, ra, acc1);
            acc2 = dot2u(v.z, ra, acc2);
            acc3 = dot2u(v.w, ra, acc3);
        }

        // conflict-free atomic reduce (lane-contiguous addresses)
        atomicAdd(&part[pb][cidx      ], acc0);
        atomicAdd(&part[pb][cidx + 128], acc1);
        atomicAdd(&part[pb][cidx + 256], acc2);
        atomicAdd(&part[pb][cidx + 384], acc3);
        __builtin_amdgcn_s_waitcnt(0xC07F);   // lgkmcnt(0)
        __builtin_amdgcn_s_barrier();         // the ONLY barrier per step

        float2 s = *(const float2*)&part[pb][h2];   // own 2 columns
        const int zb = (pb >= 1) ? (pb - 1) : 2;    // (pb+2) mod 3
        if (gate) {                                  // zero the reused buffer
            float2 z; z.x = 0.0f; z.y = 0.0f;
            *(float2*)&part[zb][h2] = z;
        }
        float an0 = tanh_fast(u_cur.x + s.x);
        float an1 = tanh_fast(u_cur.y + s.y);
        if (gate) {
            float2 st; st.x = an0; st.y = an1;
            *(float2*)&out[(size_t)t * (BB * NH) + (size_t)b * NH + h2] = st;
        }
        a_loc = pk16(an0, an1);               // next-step a, in register
        u_cur = u_next;
        pb = (pb == 2) ? 0 : (pb + 1);
    }
}

extern "C" void kernel_launch(void* const* d_in, const int* in_sizes, int n_in,
                              void* d_out, int out_size, void* d_ws, size_t ws_size,
                              hipStream_t stream) {
    const float* X   = (const float*)d_in[0];
    const float* Wax = (const float*)d_in[1];
    const float* Waa = (const float*)d_in[2];
    const float* bx  = (const float*)d_in[3];
    const float* ba  = (const float*)d_in[4];
    float* out = (float*)d_out;

    const size_t xp_dw = (size_t)BB * (NIN / 2) * TT;
    const size_t wp_dw = (size_t)(NIN / 2) * NH;
    const size_t need  = (xp_dw + wp_dw) * sizeof(unsigned);

    if (ws_size >= need) {
        unsigned* Xp = (unsigned*)d_ws;
        unsigned* Wp = Xp + xp_dw;
        const int npack = (NX4 + NW4 + 255) / 256;
        pack_f16<<<npack, 256, 0, stream>>>(X, Wax, Xp, Wp);
        dim3 g1(NH / 128, TT / 128, BB);
        inp_proj_mfma_pk<<<g1, 256, 0, stream>>>(Xp, Wp, bx, ba, out);
    } else {
        dim3 g1(NH / 128, TT / 128, BB);
        inp_proj_mfma<<<g1, 256, 0, stream>>>(X, Wax, bx, ba, out);
    }
    rnn_scan_v8<<<BB, 1024, 0, stream>>>(Waa, out);
}

// Round 6
// 920.884 us; speedup vs baseline: 3.5246x; 3.5246x over previous
//
#include <hip/hip_runtime.h>
#include <math.h>

#define BB   64
#define NIN  512
#define NH   512
#define TT   512

typedef _Float16 half2_t __attribute__((ext_vector_type(2)));
typedef _Float16 half8_t __attribute__((ext_vector_type(8)));
typedef float    f32x4  __attribute__((ext_vector_type(4)));

__device__ __forceinline__ unsigned pk16(float x, float y) {
    unsigned lo = (unsigned)__builtin_bit_cast(unsigned short, (_Float16)x);
    unsigned hi = (unsigned)__builtin_bit_cast(unsigned short, (_Float16)y);
    return lo | (hi << 16);
}

__device__ __forceinline__ float tanh_fast(float x) {
    float ax = __builtin_fabsf(x);
    float e  = __builtin_amdgcn_exp2f(-2.885390082f * ax);   // exp(-2|x|)
    float r  = (1.0f - e) * __builtin_amdgcn_rcpf(1.0f + e);
    return __builtin_copysignf(r, x);
}

// ---------------------------------------------------------------------------
// K0: pack X and Wax into half2-pair dwords (unchanged, verified).
// ---------------------------------------------------------------------------
#define NX4 (BB * (NIN / 2) * (TT / 4))
#define NW4 ((NIN / 2) * (NH / 4))

__global__ __launch_bounds__(256) void pack_f16(
    const float* __restrict__ X, const float* __restrict__ Wax,
    unsigned* __restrict__ Xp, unsigned* __restrict__ Wp)
{
    const int gid = blockIdx.x * 256 + threadIdx.x;
    if (gid < NX4) {
        const int t4 = gid & (TT / 4 - 1);
        const int pr = gid >> 7;
        const int j  = pr & (NIN / 2 - 1);
        const int b  = pr >> 8;
        float4 r0 = *(const float4*)&X[((size_t)b * NIN + 2 * j    ) * TT + t4 * 4];
        float4 r1 = *(const float4*)&X[((size_t)b * NIN + 2 * j + 1) * TT + t4 * 4];
        uint4 o;
        o.x = pk16(r0.x, r1.x); o.y = pk16(r0.y, r1.y);
        o.z = pk16(r0.z, r1.z); o.w = pk16(r0.w, r1.w);
        *(uint4*)&Xp[(size_t)pr * TT + t4 * 4] = o;
    } else {
        const int g = gid - NX4;
        if (g < NW4) {
            const int h4 = g & (NH / 4 - 1);
            const int j  = g >> 7;
            float4 r0 = *(const float4*)&Wax[((size_t)(2 * j    )) * NH + h4 * 4];
            float4 r1 = *(const float4*)&Wax[((size_t)(2 * j + 1)) * NH + h4 * 4];
            uint4 o;
            o.x = pk16(r0.x, r1.x); o.y = pk16(r0.y, r1.y);
            o.z = pk16(r0.z, r1.z); o.w = pk16(r0.w, r1.w);
            *(uint4*)&Wp[(size_t)j * NH + h4 * 4] = o;
        }
    }
}

// ---------------------------------------------------------------------------
// K1' (MFMA, packed inputs) — unchanged, verified.
// ---------------------------------------------------------------------------
__global__ __launch_bounds__(256) void inp_proj_mfma_pk(
    const unsigned* __restrict__ Xp, const unsigned* __restrict__ Wp,
    const float* __restrict__ bx, const float* __restrict__ ba,
    float* __restrict__ out)
{
    __shared__ unsigned Xsp[16][132];
    __shared__ unsigned Wsp[16][132];

    const int b   = blockIdx.z;
    const int t0  = blockIdx.y * 128;
    const int h0  = blockIdx.x * 128;
    const int tid = threadIdx.x;
    const int lane = tid & 63;
    const int wid  = tid >> 6;
    const int wm   = wid >> 1;
    const int wn   = wid & 1;
    const int q    = lane >> 4;
    const int r16  = lane & 15;

    const int lr = tid >> 4;
    const int lc = (tid & 15) * 8;

    const unsigned* Xb = Xp + (size_t)b * (NIN / 2) * TT;

    f32x4 acc[4][4] = {};

    for (int p0 = 0; p0 < NIN / 2; p0 += 16) {
        const unsigned* Arow = &Xb[(size_t)(p0 + lr) * TT + t0 + lc];
        const unsigned* Brow = &Wp[(size_t)(p0 + lr) * NH + h0 + lc];
        uint4 xa = *(const uint4*)&Arow[0];
        uint4 xb = *(const uint4*)&Arow[4];
        uint4 wa = *(const uint4*)&Brow[0];
        uint4 wb = *(const uint4*)&Brow[4];

        __syncthreads();
        *(uint4*)&Xsp[lr][lc]     = xa;
        *(uint4*)&Xsp[lr][lc + 4] = xb;
        *(uint4*)&Wsp[lr][lc]     = wa;
        *(uint4*)&Wsp[lr][lc + 4] = wb;
        __syncthreads();

        uint4 af[4], bf[4];
#pragma unroll
        for (int mt = 0; mt < 4; ++mt) {
            const int tc = wm * 64 + mt * 16 + r16;
            af[mt].x = Xsp[4 * q + 0][tc];
            af[mt].y = Xsp[4 * q + 1][tc];
            af[mt].z = Xsp[4 * q + 2][tc];
            af[mt].w = Xsp[4 * q + 3][tc];
        }
#pragma unroll
        for (int nt = 0; nt < 4; ++nt) {
            const int hc = wn * 64 + nt * 16 + r16;
            bf[nt].x = Wsp[4 * q + 0][hc];
            bf[nt].y = Wsp[4 * q + 1][hc];
            bf[nt].z = Wsp[4 * q + 2][hc];
            bf[nt].w = Wsp[4 * q + 3][hc];
        }
#pragma unroll
        for (int mt = 0; mt < 4; ++mt)
#pragma unroll
            for (int nt = 0; nt < 4; ++nt)
                acc[mt][nt] = __builtin_amdgcn_mfma_f32_16x16x32_f16(
                    __builtin_bit_cast(half8_t, af[mt]),
                    __builtin_bit_cast(half8_t, bf[nt]),
                    acc[mt][nt], 0, 0, 0);
    }

#pragma unroll
    for (int nt = 0; nt < 4; ++nt) {
        const int h = h0 + wn * 64 + nt * 16 + r16;
        const float bias = bx[h] + ba[h];
#pragma unroll
        for (int mt = 0; mt < 4; ++mt) {
            const int trow = t0 + wm * 64 + mt * 16 + q * 4;
#pragma unroll
            for (int rr = 0; rr < 4; ++rr) {
                out[(size_t)(trow + rr) * (BB * NH) + (size_t)b * NH + h] =
                    acc[mt][nt][rr] + bias;
            }
        }
    }
}

// ---------------------------------------------------------------------------
// K1 fallback (f32 inputs) — used only if ws too small. Unchanged.
// ---------------------------------------------------------------------------
__global__ __launch_bounds__(256) void inp_proj_mfma(
    const float* __restrict__ X, const float* __restrict__ Wax,
    const float* __restrict__ bx, const float* __restrict__ ba,
    float* __restrict__ out)
{
    __shared__ unsigned Xsp[16][132];
    __shared__ unsigned Wsp[16][132];

    const int b   = blockIdx.z;
    const int t0  = blockIdx.y * 128;
    const int h0  = blockIdx.x * 128;
    const int tid = threadIdx.x;
    const int lane = tid & 63;
    const int wid  = tid >> 6;
    const int wm   = wid >> 1;
    const int wn   = wid & 1;
    const int q    = lane >> 4;
    const int r16  = lane & 15;

    const int lr = tid >> 4;
    const int lc = (tid & 15) * 8;

    const float* Xb = X + (size_t)b * NIN * TT;

    f32x4 acc[4][4] = {};

    for (int i0 = 0; i0 < NIN; i0 += 32) {
        const int k0 = i0 + 2 * lr, k1 = k0 + 1;
        float4 xa0 = *(const float4*)&Xb[(size_t)k0 * TT + t0 + lc];
        float4 xa1 = *(const float4*)&Xb[(size_t)k0 * TT + t0 + lc + 4];
        float4 xb0 = *(const float4*)&Xb[(size_t)k1 * TT + t0 + lc];
        float4 xb1 = *(const float4*)&Xb[(size_t)k1 * TT + t0 + lc + 4];
        float4 wa0 = *(const float4*)&Wax[(size_t)k0 * NH + h0 + lc];
        float4 wa1 = *(const float4*)&Wax[(size_t)k0 * NH + h0 + lc + 4];
        float4 wb0 = *(const float4*)&Wax[(size_t)k1 * NH + h0 + lc];
        float4 wb1 = *(const float4*)&Wax[(size_t)k1 * NH + h0 + lc + 4];

        uint4 xp0, xp1, wp0, wp1;
        xp0.x = pk16(xa0.x, xb0.x); xp0.y = pk16(xa0.y, xb0.y);
        xp0.z = pk16(xa0.z, xb0.z); xp0.w = pk16(xa0.w, xb0.w);
        xp1.x = pk16(xa1.x, xb1.x); xp1.y = pk16(xa1.y, xb1.y);
        xp1.z = pk16(xa1.z, xb1.z); xp1.w = pk16(xa1.w, xb1.w);
        wp0.x = pk16(wa0.x, wb0.x); wp0.y = pk16(wa0.y, wb0.y);
        wp0.z = pk16(wa0.z, wb0.z); wp0.w = pk16(wa0.w, wb0.w);
        wp1.x = pk16(wa1.x, wb1.x); wp1.y = pk16(wa1.y, wb1.y);
        wp1.z = pk16(wa1.z, wb1.z); wp1.w = pk16(wa1.w, wb1.w);

        __syncthreads();
        *(uint4*)&Xsp[lr][lc]     = xp0;
        *(uint4*)&Xsp[lr][lc + 4] = xp1;
        *(uint4*)&Wsp[lr][lc]     = wp0;
        *(uint4*)&Wsp[lr][lc + 4] = wp1;
        __syncthreads();

        uint4 af[4], bf[4];
#pragma unroll
        for (int mt = 0; mt < 4; ++mt) {
            const int tc = wm * 64 + mt * 16 + r16;
            af[mt].x = Xsp[4 * q + 0][tc];
            af[mt].y = Xsp[4 * q + 1][tc];
            af[mt].z = Xsp[4 * q + 2][tc];
            af[mt].w = Xsp[4 * q + 3][tc];
        }
#pragma unroll
        for (int nt = 0; nt < 4; ++nt) {
            const int hc = wn * 64 + nt * 16 + r16;
            bf[nt].x = Wsp[4 * q + 0][hc];
            bf[nt].y = Wsp[4 * q + 1][hc];
            bf[nt].z = Wsp[4 * q + 2][hc];
            bf[nt].w = Wsp[4 * q + 3][hc];
        }
#pragma unroll
        for (int mt = 0; mt < 4; ++mt)
#pragma unroll
            for (int nt = 0; nt < 4; ++nt)
                acc[mt][nt] = __builtin_amdgcn_mfma_f32_16x16x32_f16(
                    __builtin_bit_cast(half8_t, af[mt]),
                    __builtin_bit_cast(half8_t, bf[nt]),
                    acc[mt][nt], 0, 0, 0);
    }

#pragma unroll
    for (int nt = 0; nt < 4; ++nt) {
        const int h = h0 + wn * 64 + nt * 16 + r16;
        const float bias = bx[h] + ba[h];
#pragma unroll
        for (int mt = 0; mt < 4; ++mt) {
            const int trow = t0 + wm * 64 + mt * 16 + q * 4;
#pragma unroll
            for (int rr = 0; rr < 4; ++rr) {
                out[(size_t)(trow + rr) * (BB * NH) + (size_t)b * NH + h] =
                    acc[mt][nt][rr] + bias;
            }
        }
    }
}

// ---------------------------------------------------------------------------
// K2 v9 (MFMA scan): one block per batch, 16 waves (1024 thr). Wave w owns
// output cols [32w, 32w+32) = two 16-col N-tiles, computed over FULL K=512
// via 32 mfma_f32_16x16x32_f16 per step (2 N-tiles x 16 K-tiles) — no
// k-split, no cross-wave reduce, no idle half. a_t is replicated into all
// 16 A-rows (every lane's A-frag = a[kk*32+8q+j], row-independent), so
// every lane holds a valid copy of every output — lanes 0..15 write.
// Waa resident as B-frags: K-tiles 0..11 in 96 dwords/thread (compiler may
// demote to AGPRs — MFMA reads AGPRs natively, zero tax); K-tiles 12..15 in
// LDS uint4 rows (128 KB, v6's proven conflict-free pattern). a vector in
// 1 KB double-buffered LDS; A-frag load = 1 broadcast ds_read_b128/K-tile.
// ONE barrier/step (step-t reads of buf precede barrier t; step-t+1 writes
// to the same buf follow it).
// Fragment layouts copied from the numerically verified K1:
//   A/B elem j <-> k = 8*(lane>>4)+j ; B dword d = pk16(W[k_even],W[k_odd]);
//   C col = lane&15, rows replicated.
// ---------------------------------------------------------------------------
#define RKT 12   // register-resident K-tiles per wave (of 16)
#define LKT 4    // LDS-resident K-tiles

__global__ __launch_bounds__(1024, 4) void rnn_scan_v9(
    const float* __restrict__ Waa, float* __restrict__ out)
{
    __shared__ uint4 wlds[LKT * 2][1024];        // 128 KB B-frags, [frag][tid]
    __shared__ unsigned short a_h[2][NH];        // 2 KB a_t halves, dbuf

    const int tid = threadIdx.x;
    const int b   = blockIdx.x;
    const int w   = tid >> 6;            // wave 0..15
    const int l   = tid & 63;
    const int q   = l >> 4;              // k-subgroup 0..3
    const int c0  = w * 32 + (l & 15);   // this lane's first column
    const int c1  = c0 + 16;             // second column

    // ---- preamble: build B-fragments for Waa ----
    uint4 br0[RKT], br1[RKT];            // N-tile 0 / 1, K-tiles 0..11
#pragma unroll
    for (int kk = 0; kk < RKT; ++kk) {
        const int kb = kk * 32 + 8 * q;
        uint4 v0, v1;
        v0.x = pk16(Waa[(size_t)(kb + 0) * NH + c0], Waa[(size_t)(kb + 1) * NH + c0]);
        v0.y = pk16(Waa[(size_t)(kb + 2) * NH + c0], Waa[(size_t)(kb + 3) * NH + c0]);
        v0.z = pk16(Waa[(size_t)(kb + 4) * NH + c0], Waa[(size_t)(kb + 5) * NH + c0]);
        v0.w = pk16(Waa[(size_t)(kb + 6) * NH + c0], Waa[(size_t)(kb + 7) * NH + c0]);
        v1.x = pk16(Waa[(size_t)(kb + 0) * NH + c1], Waa[(size_t)(kb + 1) * NH + c1]);
        v1.y = pk16(Waa[(size_t)(kb + 2) * NH + c1], Waa[(size_t)(kb + 3) * NH + c1]);
        v1.z = pk16(Waa[(size_t)(kb + 4) * NH + c1], Waa[(size_t)(kb + 5) * NH + c1]);
        v1.w = pk16(Waa[(size_t)(kb + 6) * NH + c1], Waa[(size_t)(kb + 7) * NH + c1]);
        br0[kk] = v0;
        br1[kk] = v1;
    }
#pragma unroll
    for (int kk = 0; kk < LKT; ++kk) {
        const int kb = (RKT + kk) * 32 + 8 * q;
        uint4 v0, v1;
        v0.x = pk16(Waa[(size_t)(kb + 0) * NH + c0], Waa[(size_t)(kb + 1) * NH + c0]);
        v0.y = pk16(Waa[(size_t)(kb + 2) * NH + c0], Waa[(size_t)(kb + 3) * NH + c0]);
        v0.z = pk16(Waa[(size_t)(kb + 4) * NH + c0], Waa[(size_t)(kb + 5) * NH + c0]);
        v0.w = pk16(Waa[(size_t)(kb + 6) * NH + c0], Waa[(size_t)(kb + 7) * NH + c0]);
        v1.x = pk16(Waa[(size_t)(kb + 0) * NH + c1], Waa[(size_t)(kb + 1) * NH + c1]);
        v1.y = pk16(Waa[(size_t)(kb + 2) * NH + c1], Waa[(size_t)(kb + 3) * NH + c1]);
        v1.z = pk16(Waa[(size_t)(kb + 4) * NH + c1], Waa[(size_t)(kb + 5) * NH + c1]);
        v1.w = pk16(Waa[(size_t)(kb + 6) * NH + c1], Waa[(size_t)(kb + 7) * NH + c1]);
        wlds[kk * 2 + 0][tid] = v0;
        wlds[kk * 2 + 1][tid] = v1;
    }

    if (tid < 256) *(unsigned*)&a_h[0][tid * 2] = 0u;   // a_0 = 0
    __syncthreads();

    const float* ub0 = out + (size_t)b * NH + c0;
    const float* ub1 = out + (size_t)b * NH + c1;
    float u0 = ub0[0], u1 = ub1[0];

    for (int t = 0; t < TT; ++t) {
        const int tn = (t + 1 < TT) ? (t + 1) : (TT - 1);
        float un0 = ub0[(size_t)tn * (BB * NH)];   // prefetch next u
        float un1 = ub1[(size_t)tn * (BB * NH)];

        const unsigned short* ac = a_h[t & 1];
        f32x4 acc0 = {}, acc1 = {};
#pragma unroll
        for (int kk = 0; kk < 16; ++kk) {
            // broadcast A-frag: halves a[kk*32 + 8q .. +7] (row-replicated)
            uint4 av = *(const uint4*)&ac[kk * 32 + q * 8];
            half8_t A = __builtin_bit_cast(half8_t, av);
            uint4 b0, b1;
            if (kk < RKT) {
                b0 = br0[kk];
                b1 = br1[kk];
            } else {
                b0 = wlds[(kk - RKT) * 2 + 0][tid];
                b1 = wlds[(kk - RKT) * 2 + 1][tid];
            }
            acc0 = __builtin_amdgcn_mfma_f32_16x16x32_f16(
                A, __builtin_bit_cast(half8_t, b0), acc0, 0, 0, 0);
            acc1 = __builtin_amdgcn_mfma_f32_16x16x32_f16(
                A, __builtin_bit_cast(half8_t, b1), acc1, 0, 0, 0);
        }

        // every lane holds the result for its cols (rows replicated): reg 0
        float an0 = tanh_fast(u0 + acc0[0]);
        float an1 = tanh_fast(u1 + acc1[0]);

        unsigned short* an = a_h[(t + 1) & 1];
        if (l < 16) {
            an[c0] = __builtin_bit_cast(unsigned short, (_Float16)an0);
            an[c1] = __builtin_bit_cast(unsigned short, (_Float16)an1);
            out[(size_t)t * (BB * NH) + (size_t)b * NH + c0] = an0;
            out[(size_t)t * (BB * NH) + (size_t)b * NH + c1] = an1;
        }
        u0 = un0;
        u1 = un1;
        __builtin_amdgcn_s_waitcnt(0xC07F);   // lgkmcnt(0)
        __builtin_amdgcn_s_barrier();         // the ONLY barrier per step
    }
}

extern "C" void kernel_launch(void* const* d_in, const int* in_sizes, int n_in,
                              void* d_out, int out_size, void* d_ws, size_t ws_size,
                              hipStream_t stream) {
    const float* X   = (const float*)d_in[0];
    const float* Wax = (const float*)d_in[1];
    const float* Waa = (const float*)d_in[2];
    const float* bx  = (const float*)d_in[3];
    const float* ba  = (const float*)d_in[4];
    float* out = (float*)d_out;

    const size_t xp_dw = (size_t)BB * (NIN / 2) * TT;
    const size_t wp_dw = (size_t)(NIN / 2) * NH;
    const size_t need  = (xp_dw + wp_dw) * sizeof(unsigned);

    if (ws_size >= need) {
        unsigned* Xp = (unsigned*)d_ws;
        unsigned* Wp = Xp + xp_dw;
        const int npack = (NX4 + NW4 + 255) / 256;
        pack_f16<<<npack, 256, 0, stream>>>(X, Wax, Xp, Wp);
        dim3 g1(NH / 128, TT / 128, BB);
        inp_proj_mfma_pk<<<g1, 256, 0, stream>>>(Xp, Wp, bx, ba, out);
    } else {
        dim3 g1(NH / 128, TT / 128, BB);
        inp_proj_mfma<<<g1, 256, 0, stream>>>(X, Wax, bx, ba, out);
    }
    rnn_scan_v9<<<BB, 1024, 0, stream>>>(Waa, out);
}